// Round 4
// baseline (940.756 us; speedup 1.0000x reference)
//
#include <hip/hip_runtime.h>
#include <math.h>

// ---- problem constants ----
#define TB        256           // threads per block = 4 waves
#define PPT       2             // positions per thread
#define POSB      512           // positions per block (256 thr x 2)
#define NPOS      131072        // B*H*W positions
#define KCODES    512
#define DIM       64
#define HW        4096          // H*W
#define LOSS_OFF  8388608ull
#define ENC_OFF   8388609ull
#define PERP_OFF  75497473ull
#define TILE_DW   (POSB * KCODES)       // 262144 dwords: block's encodings tile
#define NF4       ((TILE_DW - 4) / 4)   // 65535 float4 after the +3 align shift

__device__ __forceinline__ float tree8(float r0, float r1, float r2, float r3,
                                       float r4, float r5, float r6, float r7) {
    // numpy pairwise combine: ((r0+r1)+(r2+r3)) + ((r4+r5)+(r6+r7))
    return __fadd_rn(__fadd_rn(__fadd_rn(r0, r1), __fadd_rn(r2, r3)),
                     __fadd_rn(__fadd_rn(r4, r5), __fadd_rn(r6, r7)));
}

// Prep: ww[k] = sum(w[k]^2) in numpy pairwise order; zero counts + loss accumulator.
extern "C" __global__ __launch_bounds__(512)
void vq_prep(const float* __restrict__ w, float* __restrict__ ww,
             int* __restrict__ counts, float* __restrict__ lossAcc)
{
    const int k = threadIdx.x;                 // 512 threads
    const float* wk = w + k * DIM;
    float r[8];
    #pragma unroll
    for (int i = 0; i < 8; ++i) {
        #pragma unroll
        for (int j = 0; j < 8; ++j) {
            float v = wk[i * 8 + j];
            float pp = __fmul_rn(v, v);
            r[j] = (i == 0) ? pp : __fadd_rn(r[j], pp);
        }
    }
    ww[k] = tree8(r[0], r[1], r[2], r[3], r[4], r[5], r[6], r[7]);
    counts[k] = 0;
    if (k == 0) *lossAcc = 0.0f;
}

// R10: coalesced w load + v_readlane broadcast.
// Delivery-path history (all measured): s_load = OOO SMEM, lgkmcnt(0) drains,
// ~180us (R6/R7). LDS uniform ds_read = 16B useful / ~12cy wave transaction,
// pipe shared by 4 SIMDs, 280us (R8). Per-lane VMEM broadcast = 1 wave-VMEM
// per 16B useful, 599us (R9). All deliver <=16B/lane-instr while each lane
// needs 128KB of w per scan. Fix: ONE coalesced global_load_dwordx4 fetches
// 4 FULL ROWS per wave-instr (1KB useful, 128 loads/scan not 8192), then
// v_readlane (compile-time lane, exec-independent, exact) broadcasts each
// dword to an SGPR consumed directly by v_fma. Delivery cost moves onto the
// VALU at 64 readlane per row, amortized over P=2 positions -> ~93us VALU
// model. FP chains token-identical to R7/R8 -> argmin bit-exact.
#define RL(WV, C, SL) __int_as_float(__builtin_amdgcn_readlane(             \
        (C)==0 ? __float_as_int((WV).x) : (C)==1 ? __float_as_int((WV).y) : \
        (C)==2 ? __float_as_int((WV).z) : __float_as_int((WV).w), (SL)))

#define PROC4(WV, KB) do {                                                  \
    _Pragma("unroll")                                                       \
    for (int r = 0; r < 4; ++r) {                                           \
        const int k = (KB) + r;                                             \
        float s0[8], s1[8];                                                 \
        _Pragma("unroll")                                                   \
        for (int i = 0; i < 8; ++i) {                                       \
            _Pragma("unroll")                                               \
            for (int j = 0; j < 8; ++j) {                                   \
                const int d = i * 8 + j;                                    \
                const float wv = RL(WV, d & 3, r * 16 + (d >> 2));          \
                if (i == 0) { s0[j] = __fmul_rn(x2a[d], wv);                \
                              s1[j] = __fmul_rn(x2b[d], wv); }              \
                else        { s0[j] = __fmaf_rn(x2a[d], wv, s0[j]);         \
                              s1[j] = __fmaf_rn(x2b[d], wv, s1[j]); }       \
            }                                                               \
        }                                                                   \
        float dot0 = tree8(s0[0],s0[1],s0[2],s0[3],s0[4],s0[5],s0[6],s0[7]);\
        float dot1 = tree8(s1[0],s1[1],s1[2],s1[3],s1[4],s1[5],s1[6],s1[7]);\
        float wwk = wwlds[k];                                               \
        float t0 = __fadd_rn(A0, wwk);   /* (||x||^2+||w_k||^2), ref order */\
        float t1 = __fadd_rn(A1, wwk);                                      \
        float d0 = __fadd_rn(t0, -dot0); /* minus 2*x.w */                  \
        float d1 = __fadd_rn(t1, -dot1);                                    \
        if (d0 < best0) { best0 = d0; bk0 = k; }  /* strict <: first min */ \
        if (d1 < best1) { best1 = d1; bk1 = k; }                            \
    }                                                                       \
} while (0)

extern "C" __global__ __launch_bounds__(TB)
__attribute__((amdgpu_waves_per_eu(1)))
void vq_main(const float* __restrict__ x, const float* __restrict__ w,
             const float* __restrict__ ww, float* __restrict__ out,
             int* __restrict__ counts, float* __restrict__ lossAcc)
{
    __shared__ float wwlds[KCODES];            // 2048 B
    __shared__ int   hcount[KCODES];           // 2048 B

    const int tid = threadIdx.x;
    const int l   = tid & 63;                  // lane
    const int n0  = blockIdx.x * POSB + tid;   // first position
    const int b   = n0 >> 12;                  // 512 | 4096: one b per block
    const int hw0 = n0 & 4095;                 // second position at hw0+256

    hcount[tid]      = 0;
    hcount[tid + TB] = 0;
    wwlds[tid]       = ww[tid];                // staged once, coalesced
    wwlds[tid + TB]  = ww[tid + TB];

    // ---- prologue: TWO positions' x into VGPRs (channel stride HW); x2 = 2x;
    // A = pairwise_sum(x^2), numpy order: r[j] over i ascending, then tree8.
    const float* xp = x + ((size_t)b * DIM) * HW + hw0;
    float x2a[DIM], x2b[DIM];
    float A0, A1;
    {
        float ra[8], rb[8];
        #pragma unroll
        for (int i = 0; i < 8; ++i) {
            #pragma unroll
            for (int j = 0; j < 8; ++j) {
                const int d = i * 8 + j;
                float va = xp[(size_t)d * HW];
                float vb = xp[(size_t)d * HW + 256];
                x2a[d] = va + va;                   // exact doubling
                x2b[d] = vb + vb;
                float pa = __fmul_rn(va, va);
                float pb = __fmul_rn(vb, vb);
                ra[j] = (i == 0) ? pa : __fadd_rn(ra[j], pa);
                rb[j] = (i == 0) ? pb : __fadd_rn(rb[j], pb);
            }
        }
        A0 = tree8(ra[0], ra[1], ra[2], ra[3], ra[4], ra[5], ra[6], ra[7]);
        A1 = tree8(rb[0], rb[1], rb[2], rb[3], rb[4], rb[5], rb[6], rb[7]);
    }

    // encodings tile zero-fill setup (T0%4==1 -> +3 shift is 16B-aligned)
    const size_t T0 = ENC_OFF + (size_t)blockIdx.x * TILE_DW;
    float4* zs4 = reinterpret_cast<float4*>(out + T0 + 3);
    const float4 zero4 = make_float4(0.0f, 0.0f, 0.0f, 0.0f);
    if (tid < 3)  out[T0 + tid] = 0.0f;              // edge dwords 0,1,2
    if (tid == 3) out[T0 + (TILE_DW - 1)] = 0.0f;    // edge dword 262143

    __syncthreads();   // wwlds + hcount ready

    // ---- scan all 512 codes: wave loads 4 rows/instr coalesced
    // (lane l -> row l>>4, float4 l&15), double-buffered; readlane-broadcast.
    const float4* w4 = reinterpret_cast<const float4*>(w);
    const int rsel = (l >> 4) * 16 + (l & 15);       // row-offset*16 + f4-offset

    float best0 = INFINITY, best1 = INFINITY;
    int   bk0 = 0, bk1 = 0;

    float4 wvA = w4[rsel];                           // rows 0..3
    #pragma unroll 1
    for (int k4 = 0; k4 < 128; k4 += 2) {
        float4 wvB = w4[(k4 + 1) * 64 + rsel];       // rows 4k4+4..7
        PROC4(wvA, k4 * 4);
        {   const int m = (k4 * 2) * TB + tid;       // zero-fill interleave
            if (m < NF4) zs4[m] = zero4; }
        wvA = w4[(((k4 + 2) & 127) * 64) + rsel];    // rows 4k4+8..11 (wraps)
        PROC4(wvB, (k4 + 1) * 4);
        {   const int m = (k4 * 2 + 1) * TB + tid;
            if (m < NF4) zs4[m] = zero4; }           // m=65535 crosses edge
    }

    __syncthreads();   // zero stores drained (vmcnt(0) at barrier)

    // ---- epilogue: each thread finalizes its two positions
    out[ENC_OFF + (size_t)n0 * KCODES + bk0]         = 1.0f;
    out[ENC_OFF + (size_t)(n0 + 256) * KCODES + bk1] = 1.0f;
    atomicAdd(&hcount[bk0], 1);
    atomicAdd(&hcount[bk1], 1);

    float sse = 0.0f;
    {
        const float4* wr = reinterpret_cast<const float4*>(w + (size_t)bk0 * DIM);
        float* qo = out + ((size_t)b * DIM) * HW + hw0;
        #pragma unroll
        for (int c = 0; c < 16; ++c) {
            float4 q = wr[c];
            qo[(size_t)(4 * c + 0) * HW] = q.x;
            qo[(size_t)(4 * c + 1) * HW] = q.y;
            qo[(size_t)(4 * c + 2) * HW] = q.z;
            qo[(size_t)(4 * c + 3) * HW] = q.w;
            float e0 = q.x - 0.5f * x2a[4 * c + 0]; sse = __fmaf_rn(e0, e0, sse);
            float e1 = q.y - 0.5f * x2a[4 * c + 1]; sse = __fmaf_rn(e1, e1, sse);
            float e2 = q.z - 0.5f * x2a[4 * c + 2]; sse = __fmaf_rn(e2, e2, sse);
            float e3 = q.w - 0.5f * x2a[4 * c + 3]; sse = __fmaf_rn(e3, e3, sse);
        }
    }
    {
        const float4* wr = reinterpret_cast<const float4*>(w + (size_t)bk1 * DIM);
        float* qo = out + ((size_t)b * DIM) * HW + hw0 + 256;
        #pragma unroll
        for (int c = 0; c < 16; ++c) {
            float4 q = wr[c];
            qo[(size_t)(4 * c + 0) * HW] = q.x;
            qo[(size_t)(4 * c + 1) * HW] = q.y;
            qo[(size_t)(4 * c + 2) * HW] = q.z;
            qo[(size_t)(4 * c + 3) * HW] = q.w;
            float e0 = q.x - 0.5f * x2b[4 * c + 0]; sse = __fmaf_rn(e0, e0, sse);
            float e1 = q.y - 0.5f * x2b[4 * c + 1]; sse = __fmaf_rn(e1, e1, sse);
            float e2 = q.z - 0.5f * x2b[4 * c + 2]; sse = __fmaf_rn(e2, e2, sse);
            float e3 = q.w - 0.5f * x2b[4 * c + 3]; sse = __fmaf_rn(e3, e3, sse);
        }
    }
    // wave-level SSE reduction (64 lanes), one atomic per wave
    #pragma unroll
    for (int off = 32; off > 0; off >>= 1) sse += __shfl_down(sse, off);
    if (l == 0) atomicAdd(lossAcc, sse);

    __syncthreads();   // hcount atomics done

    // histogram drain
    {
        int c0 = hcount[tid];       if (c0) atomicAdd(&counts[tid], c0);
        int c1 = hcount[tid + TB];  if (c1) atomicAdd(&counts[tid + TB], c1);
    }
}

// Finalize: loss scalar + perplexity from histogram.
extern "C" __global__ __launch_bounds__(512)
void vq_finalize(const int* __restrict__ counts, const float* __restrict__ lossAcc,
                 float* __restrict__ out)
{
    __shared__ double sred[KCODES];
    const int t = threadIdx.x;                 // 512 threads
    double p = (double)counts[t] * (1.0 / (double)NPOS);
    sred[t] = -p * log(p + 1e-10);
    __syncthreads();
    for (int s = KCODES / 2; s > 0; s >>= 1) {
        if (t < s) sred[t] += sred[t + s];
        __syncthreads();
    }
    if (t == 0) {
        out[PERP_OFF] = (float)exp(sred[0]);
        out[LOSS_OFF] = 1.25f * (lossAcc[0] / 8388608.0f);
    }
}

extern "C" void kernel_launch(void* const* d_in, const int* in_sizes, int n_in,
                              void* d_out, int out_size, void* d_ws, size_t ws_size,
                              hipStream_t stream)
{
    const float* x = (const float*)d_in[0];    // [32,64,64,64] fp32
    const float* w = (const float*)d_in[1];    // [512,64] fp32
    float* out = (float*)d_out;

    float* ww      = (float*)d_ws;                         // 512 floats
    int*   counts  = (int*)((char*)d_ws + 2048);           // 512 ints
    float* lossAcc = (float*)((char*)d_ws + 4096);         // 1 float

    vq_prep<<<1, 512, 0, stream>>>(w, ww, counts, lossAcc);
    vq_main<<<NPOS / POSB, TB, 0, stream>>>(x, w, ww, out, counts, lossAcc);
    vq_finalize<<<1, 512, 0, stream>>>(counts, lossAcc, out);
}

// Round 5
// 569.187 us; speedup vs baseline: 1.6528x; 1.6528x over previous
//
#include <hip/hip_runtime.h>
#include <math.h>

// ---- problem constants ----
#define TB        256           // threads per block = 4 waves
#define POSB      512           // positions per block (256 thr x 2 positions)
#define NPOS      131072        // B*H*W positions
#define KCODES    512
#define DIM       64
#define HW        4096          // H*W
#define LOSS_OFF  8388608ull
#define ENC_OFF   8388609ull
#define PERP_OFF  75497473ull
#define TILE_DW   (POSB * KCODES)       // 262144 dwords: block's encodings tile
#define NF4       ((TILE_DW - 4) / 4)   // 65535 float4 after the +3 align shift

__device__ __forceinline__ float tree8(float r0, float r1, float r2, float r3,
                                       float r4, float r5, float r6, float r7) {
    // numpy pairwise combine: ((r0+r1)+(r2+r3)) + ((r4+r5)+(r6+r7))
    return __fadd_rn(__fadd_rn(__fadd_rn(r0, r1), __fadd_rn(r2, r3)),
                     __fadd_rn(__fadd_rn(r4, r5), __fadd_rn(r6, r7)));
}

// Prep: ww[k] = sum(w[k]^2) in numpy pairwise order; zero counts + loss accumulator.
extern "C" __global__ __launch_bounds__(512)
void vq_prep(const float* __restrict__ w, float* __restrict__ ww,
             int* __restrict__ counts, float* __restrict__ lossAcc)
{
    const int k = threadIdx.x;                 // 512 threads
    const float* wk = w + k * DIM;
    float r[8];
    #pragma unroll
    for (int i = 0; i < 8; ++i) {
        #pragma unroll
        for (int j = 0; j < 8; ++j) {
            float v = wk[i * 8 + j];
            float pp = __fmul_rn(v, v);
            r[j] = (i == 0) ? pp : __fadd_rn(r[j], pp);
        }
    }
    ww[k] = tree8(r[0], r[1], r[2], r[3], r[4], r[5], r[6], r[7]);
    counts[k] = 0;
    if (k == 0) *lossAcc = 0.0f;
}

// R11: s_load path restored, K-split removed.
// Delivery ledger (all measured): s_load ~180us (R6/R7), LDS-broadcast 280us
// (R8), VMEM-broadcast 599us (R9), readlane 696us (R10). s_load wins: the FMA
// consumes the SGPR operand for FREE; its only cost is the un-prefetchable
// lgkmcnt(0) drain (SMEM is out-of-order; a 64-dword row can't double-buffer
// in the 102-SGPR file). R6/R7's remaining flaw: the 4-way K-split streamed
// 4 DIFFERENT 32KB row-groups through one ~16KB shared scalar cache ->
// every row missed (~250cy) for every wave. Fix: ALL waves scan ALL 512 rows
// in the SAME order -> first toucher misses, the CU's other waves hit sK$
// (~40cy). Also kills the cdist/ckidx merge: each thread owns its 2 positions
// end-to-end, epilogue on all 256 threads. ww[k] s_loaded in the same drain
// (no LDS, no lgkm mixing in the hot loop). Grid 256 = 1 block/CU.
// FP chains token-identical to R7/R8/R10 -> argmin bit-exact.
extern "C" __global__ __launch_bounds__(TB)
__attribute__((amdgpu_waves_per_eu(1)))
void vq_main(const float* __restrict__ x, const float* __restrict__ w,
             const float* __restrict__ ww, float* __restrict__ out,
             int* __restrict__ counts, float* __restrict__ lossAcc)
{
    __shared__ int hcount[KCODES];             // 2048 B

    const int tid = threadIdx.x;
    const int l   = tid & 63;                  // lane (loss reduction)
    const int n0  = blockIdx.x * POSB + tid;   // first position
    const int b   = n0 >> 12;                  // 512 | 4096: one b per block
    const int hw0 = n0 & 4095;                 // second position at hw0+256

    hcount[tid]      = 0;
    hcount[tid + TB] = 0;

    // ---- prologue: TWO positions' x into VGPRs (channel stride HW); x2 = 2x;
    // A = pairwise_sum(x^2), numpy order: r[j] over i ascending, then tree8.
    const float* xp = x + ((size_t)b * DIM) * HW + hw0;
    float x2a[DIM], x2b[DIM];
    float A0, A1;
    {
        float ra[8], rb[8];
        #pragma unroll
        for (int i = 0; i < 8; ++i) {
            #pragma unroll
            for (int j = 0; j < 8; ++j) {
                const int d = i * 8 + j;
                float va = xp[(size_t)d * HW];
                float vb = xp[(size_t)d * HW + 256];
                x2a[d] = va + va;                   // exact doubling
                x2b[d] = vb + vb;
                float pa = __fmul_rn(va, va);
                float pb = __fmul_rn(vb, vb);
                ra[j] = (i == 0) ? pa : __fadd_rn(ra[j], pa);
                rb[j] = (i == 0) ? pb : __fadd_rn(rb[j], pb);
            }
        }
        A0 = tree8(ra[0], ra[1], ra[2], ra[3], ra[4], ra[5], ra[6], ra[7]);
        A1 = tree8(rb[0], rb[1], rb[2], rb[3], rb[4], rb[5], rb[6], rb[7]);
    }

    // encodings tile zero-fill setup (T0%4==1 -> +3 shift is 16B-aligned)
    const size_t T0 = ENC_OFF + (size_t)blockIdx.x * TILE_DW;
    float4* zs4 = reinterpret_cast<float4*>(out + T0 + 3);
    const float4 zero4 = make_float4(0.0f, 0.0f, 0.0f, 0.0f);
    if (tid < 3)  out[T0 + tid] = 0.0f;              // edge dwords 0,1,2
    if (tid == 3) out[T0 + (TILE_DW - 1)] = 0.0f;    // edge dword 262143

    __syncthreads();   // hcount ready

    // ---- scan ALL 512 codes, same order in every wave (sK$ sharing);
    // w row + ww[k] via wave-uniform s_load (SGPR operands, free in FMA);
    // interleave the coalesced float4 zero-fill of the encodings tile.
    float best0 = INFINITY, best1 = INFINITY;
    int   bk0 = 0, bk1 = 0;

    #pragma unroll 1
    for (int k = 0; k < KCODES; ++k) {
        const float* wk = w + (size_t)k * DIM;   // uniform -> s_load path
        float s0[8], s1[8];
        #pragma unroll
        for (int i = 0; i < 8; ++i) {
            #pragma unroll
            for (int j = 0; j < 8; ++j) {
                const int d = i * 8 + j;
                const float wv = wk[d];          // 1 SGPR operand per FMA
                if (i == 0) { s0[j] = __fmul_rn(x2a[d], wv);     // == fmaf(a,b,0)
                              s1[j] = __fmul_rn(x2b[d], wv); }
                else        { s0[j] = __fmaf_rn(x2a[d], wv, s0[j]);
                              s1[j] = __fmaf_rn(x2b[d], wv, s1[j]); }
            }
        }
        float dot0 = tree8(s0[0],s0[1],s0[2],s0[3],s0[4],s0[5],s0[6],s0[7]);
        float dot1 = tree8(s1[0],s1[1],s1[2],s1[3],s1[4],s1[5],s1[6],s1[7]);
        float wwk  = ww[k];                      // uniform s_load, same drain
        float t0   = __fadd_rn(A0, wwk);         // (||x||^2+||w_k||^2), ref order
        float t1   = __fadd_rn(A1, wwk);
        float d0   = __fadd_rn(t0, -dot0);       // minus 2*x.w
        float d1   = __fadd_rn(t1, -dot1);
        if (d0 < best0) { best0 = d0; bk0 = k; } // strict <: first min k
        if (d1 < best1) { best1 = d1; bk1 = k; }

        if ((k & 1) == 0) {                      // 256 float4 per thread total
            const int m = (k >> 1) * TB + tid;   // covers [0, 65536)
            if (m < NF4) zs4[m] = zero4;         // m=65535 crosses the tile edge
        }
    }

    __syncthreads();   // zero stores drained (vmcnt(0) at barrier)

    // ---- epilogue: each thread finalizes its two positions
    out[ENC_OFF + (size_t)n0 * KCODES + bk0]         = 1.0f;
    out[ENC_OFF + (size_t)(n0 + 256) * KCODES + bk1] = 1.0f;
    atomicAdd(&hcount[bk0], 1);
    atomicAdd(&hcount[bk1], 1);

    float sse = 0.0f;
    {
        const float4* wr = reinterpret_cast<const float4*>(w + (size_t)bk0 * DIM);
        float* qo = out + ((size_t)b * DIM) * HW + hw0;
        #pragma unroll
        for (int c = 0; c < 16; ++c) {
            float4 q = wr[c];
            qo[(size_t)(4 * c + 0) * HW] = q.x;
            qo[(size_t)(4 * c + 1) * HW] = q.y;
            qo[(size_t)(4 * c + 2) * HW] = q.z;
            qo[(size_t)(4 * c + 3) * HW] = q.w;
            float e0 = q.x - 0.5f * x2a[4 * c + 0]; sse = __fmaf_rn(e0, e0, sse);
            float e1 = q.y - 0.5f * x2a[4 * c + 1]; sse = __fmaf_rn(e1, e1, sse);
            float e2 = q.z - 0.5f * x2a[4 * c + 2]; sse = __fmaf_rn(e2, e2, sse);
            float e3 = q.w - 0.5f * x2a[4 * c + 3]; sse = __fmaf_rn(e3, e3, sse);
        }
    }
    {
        const float4* wr = reinterpret_cast<const float4*>(w + (size_t)bk1 * DIM);
        float* qo = out + ((size_t)b * DIM) * HW + hw0 + 256;
        #pragma unroll
        for (int c = 0; c < 16; ++c) {
            float4 q = wr[c];
            qo[(size_t)(4 * c + 0) * HW] = q.x;
            qo[(size_t)(4 * c + 1) * HW] = q.y;
            qo[(size_t)(4 * c + 2) * HW] = q.z;
            qo[(size_t)(4 * c + 3) * HW] = q.w;
            float e0 = q.x - 0.5f * x2b[4 * c + 0]; sse = __fmaf_rn(e0, e0, sse);
            float e1 = q.y - 0.5f * x2b[4 * c + 1]; sse = __fmaf_rn(e1, e1, sse);
            float e2 = q.z - 0.5f * x2b[4 * c + 2]; sse = __fmaf_rn(e2, e2, sse);
            float e3 = q.w - 0.5f * x2b[4 * c + 3]; sse = __fmaf_rn(e3, e3, sse);
        }
    }
    // wave-level SSE reduction (64 lanes), one atomic per wave
    #pragma unroll
    for (int off = 32; off > 0; off >>= 1) sse += __shfl_down(sse, off);
    if (l == 0) atomicAdd(lossAcc, sse);

    __syncthreads();   // hcount atomics done

    // histogram drain
    {
        int c0 = hcount[tid];       if (c0) atomicAdd(&counts[tid], c0);
        int c1 = hcount[tid + TB];  if (c1) atomicAdd(&counts[tid + TB], c1);
    }
}

// Finalize: loss scalar + perplexity from histogram.
extern "C" __global__ __launch_bounds__(512)
void vq_finalize(const int* __restrict__ counts, const float* __restrict__ lossAcc,
                 float* __restrict__ out)
{
    __shared__ double sred[KCODES];
    const int t = threadIdx.x;                 // 512 threads
    double p = (double)counts[t] * (1.0 / (double)NPOS);
    sred[t] = -p * log(p + 1e-10);
    __syncthreads();
    for (int s = KCODES / 2; s > 0; s >>= 1) {
        if (t < s) sred[t] += sred[t + s];
        __syncthreads();
    }
    if (t == 0) {
        out[PERP_OFF] = (float)exp(sred[0]);
        out[LOSS_OFF] = 1.25f * (lossAcc[0] / 8388608.0f);
    }
}

extern "C" void kernel_launch(void* const* d_in, const int* in_sizes, int n_in,
                              void* d_out, int out_size, void* d_ws, size_t ws_size,
                              hipStream_t stream)
{
    const float* x = (const float*)d_in[0];    // [32,64,64,64] fp32
    const float* w = (const float*)d_in[1];    // [512,64] fp32
    float* out = (float*)d_out;

    float* ww      = (float*)d_ws;                         // 512 floats
    int*   counts  = (int*)((char*)d_ws + 2048);           // 512 ints
    float* lossAcc = (float*)((char*)d_ws + 4096);         // 1 float

    vq_prep<<<1, 512, 0, stream>>>(w, ww, counts, lossAcc);
    vq_main<<<NPOS / POSB, TB, 0, stream>>>(x, w, ww, out, counts, lossAcc);
    vq_finalize<<<1, 512, 0, stream>>>(counts, lossAcc, out);
}

// Round 6
// 434.090 us; speedup vs baseline: 2.1672x; 1.3112x over previous
//
#include <hip/hip_runtime.h>
#include <math.h>

// ---- problem constants ----
#define TB        256           // threads per block = 4 waves
#define POSB      64            // positions per block (1 per wave-0 lane)
#define NPOS      131072        // B*H*W positions
#define KCODES    512
#define DIM       64
#define HW        4096          // H*W
#define LOSS_OFF  8388608ull
#define ENC_OFF   8388609ull
#define PERP_OFF  75497473ull
#define TILE_DW   (POSB * KCODES)       // 32768 dwords: block's encodings tile
#define NF4       ((TILE_DW - 4) / 4)   // 8191 float4 after the +3 align shift
#define SCST      516                   // scores LDS row stride (dwords, 16B-ok)
#define TAU       2.0e-4f               // rigorous screen slack (see R12 notes)

// dynamic-LDS carve offsets (bytes)
#define SC_OFF    0                     // float  [64][516]  = 132096
#define AF_OFF    132096                // ushort [2][4][2][64][8] = 16384
#define QM_OFF    148480                // float  [4][64]    = 1024
#define GM_OFF    149504                // float  [64]       = 256
#define CC_OFF    149760                // int    [64]       = 256
#define CL_OFF    150016                // int    [64][4]    = 1024
#define HC_OFF    151040                // int    [512]      = 2048
#define SMEM_SZ   153088

typedef __attribute__((ext_vector_type(8))) short bf16x8;   // 8 bf16 = 4 VGPR
typedef __attribute__((ext_vector_type(4))) float f32x4;

__device__ __forceinline__ float tree8(float r0, float r1, float r2, float r3,
                                       float r4, float r5, float r6, float r7) {
    // numpy pairwise combine: ((r0+r1)+(r2+r3)) + ((r4+r5)+(r6+r7))
    return __fadd_rn(__fadd_rn(__fadd_rn(r0, r1), __fadd_rn(r2, r3)),
                     __fadd_rn(__fadd_rn(r4, r5), __fadd_rn(r6, r7)));
}

// R12 prep: ww[k] exact pairwise; w packed into MFMA B-fragments (bf16 hi/lo
// truncation split: hi = top-16 bits (exact), lo = bf16_trunc(v - hi)).
// B-frag convention (16x16x32): lane lf holds col n = lf&15, k = (lf>>4)*8+j.
extern "C" __global__ __launch_bounds__(512)
void vq_prep(const float* __restrict__ w, float* __restrict__ ww,
             int* __restrict__ counts, float* __restrict__ lossAcc,
             unsigned short* __restrict__ wfrag)
{
    const int k = threadIdx.x;                 // 512 threads = codes
    const float* wk = w + k * DIM;
    const int ct = k >> 4, n = k & 15;
    float r[8];
    #pragma unroll
    for (int i = 0; i < 8; ++i) {
        #pragma unroll
        for (int j = 0; j < 8; ++j) {
            const int d = i * 8 + j;
            float v = wk[d];
            float pp = __fmul_rn(v, v);
            r[j] = (i == 0) ? pp : __fadd_rn(r[j], pp);
            // fragment pack (any consistent k-permutation cancels vs A-side)
            unsigned int hb = __float_as_uint(v) & 0xFFFF0000u;
            float rr = v - __uint_as_float(hb);            // exact residual
            unsigned short hs = (unsigned short)(hb >> 16);
            unsigned short ls = (unsigned short)(__float_as_uint(rr) >> 16);
            const int q = d >> 5, kk = d & 31;
            const int lf = ((kk >> 3) << 4) + n, j8 = kk & 7;
            wfrag[((((0 * 32 + ct) * 2 + q) * 64 + lf) << 3) + j8] = hs;
            wfrag[((((1 * 32 + ct) * 2 + q) * 64 + lf) << 3) + j8] = ls;
        }
    }
    ww[k] = tree8(r[0], r[1], r[2], r[3], r[4], r[5], r[6], r[7]);
    counts[k] = 0;
    if (k == 0) *lossAcc = 0.0f;
}

// R12: MFMA screen + exact rescue.
// Delivery ledger closed (R6-R11: s_load 180 / LDS-bcast 280 / VMEM-bcast 599
// / readlane 696 us): the exact-chain inner loop has a ~180us operand-delivery
// wall. The chain is only needed to PICK argmin, so: screen all 512 scores
// s = ww - 2x.w per position via bf16 hi/lo-split MFMA (3 terms, ww in C-init;
// A = -2x is per-position constant-free). Rigorous |s - exact| <= ~3e-5 and
// chain-vs-real slack ~2e-5 => true argmin is within TAU=2e-4 of approx min.
// Scores staged in 132KB dynamic LDS, scanned full-width per-lane (no
// broadcast). ~97% of positions have 1 candidate (top-2 gap ~6e-3); rest get
// the token-identical exact chain on 2-4 candidates (lex-min == ascending
// strict-<); >4 (astronomically rare) -> full exact scan. Guaranteed exact.
extern "C" __global__ __launch_bounds__(TB, 1)
void vq_main(const float* __restrict__ x, const float* __restrict__ w,
             const float* __restrict__ ww, float* __restrict__ out,
             int* __restrict__ counts, float* __restrict__ lossAcc,
             const unsigned short* __restrict__ wfrag)
{
    extern __shared__ __align__(16) char smem[];
    float*          sc     = (float*)(smem + SC_OFF);
    unsigned short* aF     = (unsigned short*)(smem + AF_OFF);
    float*          qminv  = (float*)(smem + QM_OFF);
    float*          gminA  = (float*)(smem + GM_OFF);
    int*            ccount = (int*)(smem + CC_OFF);
    int*            clist  = (int*)(smem + CL_OFF);
    int*            hcount = (int*)(smem + HC_OFF);

    const int tid = threadIdx.x;
    const int l   = tid & 63;                  // lane
    const int wv  = tid >> 6;                  // wave id
    const int n0  = blockIdx.x * POSB;         // 64 | 4096: one b per block
    const int b   = n0 >> 12;
    const int hw0 = n0 & 4095;

    hcount[tid]      = 0;
    hcount[tid + TB] = 0;
    if (tid < 64) ccount[tid] = 0;

    // ---- prologue (wave 0): lane l owns position n0+l. Exact x2=2x and
    // A = pairwise_sum(x^2) (d ascending == i-major: bit-identical chain);
    // write A-fragments of m2x = -2x (hi/lo split) into LDS.
    float x2[DIM];
    float A = 0.0f;
    if (wv == 0) {
        const float* xp = x + ((size_t)b * DIM) * HW + (hw0 + l);
        float r[8];
        #pragma unroll
        for (int d = 0; d < DIM; ++d) {
            float v = xp[(size_t)d * HW];
            x2[d] = v + v;                      // exact doubling
            float pp = __fmul_rn(v, v);
            const int j = d & 7;
            r[j] = (d < 8) ? pp : __fadd_rn(r[j], pp);
            float m2 = -(v + v);                // exact
            unsigned int hb = __float_as_uint(m2) & 0xFFFF0000u;
            float rr = m2 - __uint_as_float(hb);
            const int q = d >> 5, kk = d & 31;
            const int lf = (l & 15) + ((kk >> 3) << 4), j8 = kk & 7;
            const int pt = l >> 4;
            aF[((((0 * 4 + pt) * 2 + q) * 64 + lf) << 3) + j8] =
                (unsigned short)(hb >> 16);
            aF[((((1 * 4 + pt) * 2 + q) * 64 + lf) << 3) + j8] =
                (unsigned short)(__float_as_uint(rr) >> 16);
        }
        A = tree8(r[0], r[1], r[2], r[3], r[4], r[5], r[6], r[7]);
    }
    __syncthreads();   // A-frags visible

    // ---- MFMA screen: wave wv owns pos-tile pt=wv (rows), all 32 code-tiles.
    const bf16x8* aFv = reinterpret_cast<const bf16x8*>(aF);
    const bf16x8 ah0 = aFv[((0 * 4 + wv) * 2 + 0) * 64 + l];
    const bf16x8 ah1 = aFv[((0 * 4 + wv) * 2 + 1) * 64 + l];
    const bf16x8 al0 = aFv[((1 * 4 + wv) * 2 + 0) * 64 + l];
    const bf16x8 al1 = aFv[((1 * 4 + wv) * 2 + 1) * 64 + l];

    const bf16x8* wf = reinterpret_cast<const bf16x8*>(wfrag);
    bf16x8 BB[4][4];                           // depth-4 prefetch (static idx)
    float  wwb[4];
    #pragma unroll
    for (int u = 0; u < 4; ++u) {
        BB[u][0] = wf[((0 * 32 + u) * 2 + 0) * 64 + l];   // hi q0
        BB[u][1] = wf[((0 * 32 + u) * 2 + 1) * 64 + l];   // hi q1
        BB[u][2] = wf[((1 * 32 + u) * 2 + 0) * 64 + l];   // lo q0
        BB[u][3] = wf[((1 * 32 + u) * 2 + 1) * 64 + l];   // lo q1
        wwb[u] = ww[u * 16 + (l & 15)];
    }
    #pragma unroll 1
    for (int c4 = 0; c4 < 8; ++c4) {
        #pragma unroll
        for (int u = 0; u < 4; ++u) {
            const int ct = c4 * 4 + u;
            f32x4 acc = { wwb[u], wwb[u], wwb[u], wwb[u] };   // C-init = ww[col]
            acc = __builtin_amdgcn_mfma_f32_16x16x32_bf16(al0, BB[u][0], acc, 0, 0, 0);
            acc = __builtin_amdgcn_mfma_f32_16x16x32_bf16(ah0, BB[u][2], acc, 0, 0, 0);
            acc = __builtin_amdgcn_mfma_f32_16x16x32_bf16(ah0, BB[u][0], acc, 0, 0, 0);
            acc = __builtin_amdgcn_mfma_f32_16x16x32_bf16(al1, BB[u][1], acc, 0, 0, 0);
            acc = __builtin_amdgcn_mfma_f32_16x16x32_bf16(ah1, BB[u][3], acc, 0, 0, 0);
            acc = __builtin_amdgcn_mfma_f32_16x16x32_bf16(ah1, BB[u][1], acc, 0, 0, 0);
            const int nt = (ct + 4) & 31;      // tail wraps; harmless
            BB[u][0] = wf[((0 * 32 + nt) * 2 + 0) * 64 + l];
            BB[u][1] = wf[((0 * 32 + nt) * 2 + 1) * 64 + l];
            BB[u][2] = wf[((1 * 32 + nt) * 2 + 0) * 64 + l];
            BB[u][3] = wf[((1 * 32 + nt) * 2 + 1) * 64 + l];
            wwb[u] = ww[nt * 16 + (l & 15)];
            // C/D layout (m89-verified): col=lane&15, row=(lane>>4)*4+reg
            const int col  = ct * 16 + (l & 15);
            const int prow = wv * 16 + ((l >> 4) << 2);
            sc[(prow + 0) * SCST + col] = acc[0];
            sc[(prow + 1) * SCST + col] = acc[1];
            sc[(prow + 2) * SCST + col] = acc[2];
            sc[(prow + 3) * SCST + col] = acc[3];
        }
    }
    __syncthreads();   // scores complete

    // ---- scan: 4 threads/pos, quarter mins; interleave encodings zero-fill.
    const size_t T0 = ENC_OFF + (size_t)blockIdx.x * TILE_DW;
    float4* zs4 = reinterpret_cast<float4*>(out + T0 + 3);   // T0%4==1 -> aligned
    const float4 zero4 = make_float4(0.0f, 0.0f, 0.0f, 0.0f);
    if (tid < 3)  out[T0 + tid] = 0.0f;              // edge dwords 0,1,2
    if (tid == 3) out[T0 + (TILE_DW - 1)] = 0.0f;    // edge dword 32767

    const int sp = tid & 63;                   // position
    const int qt = tid >> 6;                   // quarter (== wave id)
    const float4* qbase =
        reinterpret_cast<const float4*>(&sc[sp * SCST + qt * 128]);
    float vmin = INFINITY;
    #pragma unroll 1
    for (int it = 0; it < 32; ++it) {
        const int m = it * TB + tid;           // 8192 slots cover 8191
        if (m < NF4) zs4[m] = zero4;
        float4 s4 = qbase[it];
        vmin = fminf(vmin, fminf(fminf(s4.x, s4.y), fminf(s4.z, s4.w)));
    }
    qminv[qt * 64 + sp] = vmin;
    __syncthreads();
    if (tid < 64)
        gminA[tid] = fminf(fminf(qminv[0 * 64 + tid], qminv[1 * 64 + tid]),
                           fminf(qminv[2 * 64 + tid], qminv[3 * 64 + tid]));
    __syncthreads();

    // ---- candidate pass: all k with s <= gmin + TAU (argmin provably inside)
    {
        const float thr = gminA[sp] + TAU;
        #pragma unroll 1
        for (int it = 0; it < 32; ++it) {
            float4 s4 = qbase[it];
            const int kb = qt * 128 + it * 4;
            if (s4.x <= thr) { int s = atomicAdd(&ccount[sp], 1); if (s < 4) clist[sp * 4 + s] = kb + 0; }
            if (s4.y <= thr) { int s = atomicAdd(&ccount[sp], 1); if (s < 4) clist[sp * 4 + s] = kb + 1; }
            if (s4.z <= thr) { int s = atomicAdd(&ccount[sp], 1); if (s < 4) clist[sp * 4 + s] = kb + 2; }
            if (s4.w <= thr) { int s = atomicAdd(&ccount[sp], 1); if (s < 4) clist[sp * 4 + s] = kb + 3; }
        }
    }
    __syncthreads();   // zero-fill drained (vmcnt(0) at barrier); lists ready

    // ---- rescue + epilogue (wave 0; lane l = position n0+l, exact x2/A live)
    if (wv == 0) {
        int bestk;
        const int cnt = ccount[l];
        if (cnt == 1) {
            bestk = clist[l * 4 + 0];
        } else if (cnt <= 4) {
            float bd = INFINITY; int bk = KCODES;
            for (int c = 0; c < cnt; ++c) {
                const int k = clist[l * 4 + c];
                const float* wk = w + (size_t)k * DIM;
                float s[8];
                #pragma unroll
                for (int i = 0; i < 8; ++i) {
                    #pragma unroll
                    for (int j = 0; j < 8; ++j) {
                        const int d = i * 8 + j;
                        float wvv = wk[d];
                        if (i == 0) s[j] = __fmul_rn(x2[d], wvv);
                        else        s[j] = __fmaf_rn(x2[d], wvv, s[j]);
                    }
                }
                float dot  = tree8(s[0], s[1], s[2], s[3], s[4], s[5], s[6], s[7]);
                float dist = __fadd_rn(__fadd_rn(A, ww[k]), -dot);
                if (dist < bd || (dist == bd && k < bk)) { bd = dist; bk = k; }
            }
            bestk = bk;
        } else {                               // guaranteed path (≈never)
            float bd = INFINITY; int bk = 0;
            #pragma unroll 1
            for (int k = 0; k < KCODES; ++k) {
                const float* wk = w + (size_t)k * DIM;
                float s[8];
                #pragma unroll
                for (int i = 0; i < 8; ++i) {
                    #pragma unroll
                    for (int j = 0; j < 8; ++j) {
                        const int d = i * 8 + j;
                        float wvv = wk[d];
                        if (i == 0) s[j] = __fmul_rn(x2[d], wvv);
                        else        s[j] = __fmaf_rn(x2[d], wvv, s[j]);
                    }
                }
                float dot  = tree8(s[0], s[1], s[2], s[3], s[4], s[5], s[6], s[7]);
                float dist = __fadd_rn(__fadd_rn(A, ww[k]), -dot);
                if (dist < bd) { bd = dist; bk = k; }   // ascending strict <
            }
            bestk = bk;
        }

        const int n = n0 + l;
        out[ENC_OFF + (size_t)n * KCODES + bestk] = 1.0f;   // one-hot
        atomicAdd(&hcount[bestk], 1);

        const float4* wr = reinterpret_cast<const float4*>(w + (size_t)bestk * DIM);
        float* qo = out + ((size_t)b * DIM) * HW + (hw0 + l);
        float sse = 0.0f;
        #pragma unroll
        for (int c = 0; c < 16; ++c) {
            float4 q = wr[c];
            qo[(size_t)(4 * c + 0) * HW] = q.x;
            qo[(size_t)(4 * c + 1) * HW] = q.y;
            qo[(size_t)(4 * c + 2) * HW] = q.z;
            qo[(size_t)(4 * c + 3) * HW] = q.w;
            float e0 = q.x - 0.5f * x2[4 * c + 0]; sse = __fmaf_rn(e0, e0, sse);
            float e1 = q.y - 0.5f * x2[4 * c + 1]; sse = __fmaf_rn(e1, e1, sse);
            float e2 = q.z - 0.5f * x2[4 * c + 2]; sse = __fmaf_rn(e2, e2, sse);
            float e3 = q.w - 0.5f * x2[4 * c + 3]; sse = __fmaf_rn(e3, e3, sse);
        }
        #pragma unroll
        for (int off = 32; off > 0; off >>= 1) sse += __shfl_down(sse, off);
        if (l == 0) atomicAdd(lossAcc, sse);
    }
    __syncthreads();   // hcount atomics done

    // histogram drain
    {
        int c0 = hcount[tid];       if (c0) atomicAdd(&counts[tid], c0);
        int c1 = hcount[tid + TB];  if (c1) atomicAdd(&counts[tid + TB], c1);
    }
}

// Finalize: loss scalar + perplexity from histogram.
extern "C" __global__ __launch_bounds__(512)
void vq_finalize(const int* __restrict__ counts, const float* __restrict__ lossAcc,
                 float* __restrict__ out)
{
    __shared__ double sred[KCODES];
    const int t = threadIdx.x;                 // 512 threads
    double p = (double)counts[t] * (1.0 / (double)NPOS);
    sred[t] = -p * log(p + 1e-10);
    __syncthreads();
    for (int s = KCODES / 2; s > 0; s >>= 1) {
        if (t < s) sred[t] += sred[t + s];
        __syncthreads();
    }
    if (t == 0) {
        out[PERP_OFF] = (float)exp(sred[0]);
        out[LOSS_OFF] = 1.25f * (lossAcc[0] / 8388608.0f);
    }
}

extern "C" void kernel_launch(void* const* d_in, const int* in_sizes, int n_in,
                              void* d_out, int out_size, void* d_ws, size_t ws_size,
                              hipStream_t stream)
{
    const float* x = (const float*)d_in[0];    // [32,64,64,64] fp32
    const float* w = (const float*)d_in[1];    // [512,64] fp32
    float* out = (float*)d_out;

    float* ww              = (float*)d_ws;                      // 512 floats
    int*   counts          = (int*)((char*)d_ws + 2048);        // 512 ints
    float* lossAcc         = (float*)((char*)d_ws + 4096);      // 1 float
    unsigned short* wfrag  = (unsigned short*)((char*)d_ws + 8192);  // 128KB frags

    vq_prep<<<1, 512, 0, stream>>>(w, ww, counts, lossAcc, wfrag);
    vq_main<<<NPOS / POSB, TB, SMEM_SZ, stream>>>(x, w, ww, out, counts,
                                                  lossAcc, wfrag);
    vq_finalize<<<1, 512, 0, stream>>>(counts, lossAcc, out);
}